// Round 1
// baseline (2579.997 us; speedup 1.0000x reference)
//
#include <hip/hip_runtime.h>
#include <stdint.h>
#include <stddef.h>

#define DIM    1024
#define NBATCH 8
#define SEQL   2048
#define JSUM   512
#define SPMAX  2304

typedef unsigned long long ull;
typedef __attribute__((ext_vector_type(8))) __bf16 bf16x8;
typedef __attribute__((ext_vector_type(8))) short  short8;
typedef __attribute__((ext_vector_type(4))) float  floatx4;

__device__ __forceinline__ short f2bf(float f) {
  unsigned u = __builtin_bit_cast(unsigned, f);
  u = (u + 0x7fffu + ((u >> 16) & 1u)) >> 16;   // RNE
  return (short)u;
}
__device__ __forceinline__ float bf2f(short s) {
  unsigned u = ((unsigned)(unsigned short)s) << 16;
  return __builtin_bit_cast(float, u);
}

// NOTE: the intrinsic's imm-offset arg applies to BOTH global and LDS
// addresses — always pass 0 and do pointer arithmetic on both sides.
__device__ __forceinline__ void glds16(const short* g, short8* l) {
  __builtin_amdgcn_global_load_lds(
      (const __attribute__((address_space(1))) unsigned int*)g,
      (__attribute__((address_space(3))) unsigned int*)l, 16, 0, 0);
}

// Counted vmcnt wait (T4): never drain to 0 inside the K-loop.
#define VMCNT(n) do { asm volatile("s_waitcnt vmcnt(" #n ")" ::: "memory"); \
                      __builtin_amdgcn_sched_barrier(0); } while (0)

// Raw barrier WITHOUT the implicit s_waitcnt vmcnt(0) that __syncthreads()
// emits (that drain is the ~65% stall in the old 2-phase kernel).
// Memory-clobber asm pins LDS ops on their side of the barrier at IR level.
__device__ __forceinline__ void barrier_raw() {
  asm volatile("" ::: "memory");
  __builtin_amdgcn_s_barrier();
  asm volatile("" ::: "memory");
}

// ---------------------------------------------------------------------------
// NT GEMM: C[m,n] = sum_k A[m,k]*B[n,k]. A: M x K row-major, B: N x K row-major.
// 256x256 tile, 512 threads (8 waves, 2M x 4N), BK=64, double-buffered LDS
// (2 x 64 KiB), counted-vmcnt pipeline (8-phase-style schedule, T3+T4+T5).
// Requires M%256==0, N%256==0, K%64==0, K>=192 (nt>=3).
// MODE 0: C bf16            MODE 1: C bf16 + bias[n]
// MODE 2: C bf16 + bias[m]  MODE 3: f32 scatter rows (+bias[n])
// SWIZ: gridDim.z==8 assumed; batch = lin&7 pins batch->XCD.
// LDS fragment-major: 16B block (k8,row) at k8*256+row; k8 in 0..7 (BK=64).
// Conflict-free (measured 0 on the 128 version) and glds-linear-order safe.
//
// Pipeline safety argument:
//  - loads for tile t+2 (into buf[t&1]) are issued only AFTER the barrier
//    that follows the last ds_read of tile t (all waves' reads complete
//    before their MFMA lgkmcnt, which precedes that barrier);
//  - first ds_read of tile t+1 happens only after each wave's VMCNT(8)
//    (its 8 newest loads = tile t+2's) plus a barrier, so ALL waves' tile
//    t+1 loads have landed.
// ---------------------------------------------------------------------------
template<int MODE, bool SWIZ>
__global__ __launch_bounds__(512)
void gemm_nt(const short* __restrict__ A, ull sA,
             const short* __restrict__ Bm, ull sB,
             short* __restrict__ Cb, ull sC,
             int N, int Kd,
             const float* __restrict__ bias,
             float* __restrict__ dst0, int t_lo, int t_hi, int outT,
             float* __restrict__ dstSp, int t_sp, int Spad)
{
  int tn, tm, bz;
  if (SWIZ) {
    const unsigned gx = gridDim.x;
    ull lin = blockIdx.x + (ull)gx * (blockIdx.y + (ull)gridDim.y * blockIdx.z);
    bz = (int)(lin & 7);
    ull s = lin >> 3;
    tn = (int)(s % gx);
    tm = (int)(s / gx);
  } else {
    tn = blockIdx.x; tm = blockIdx.y; bz = blockIdx.z;
  }

  A  += (ull)bz * sA;
  Bm += (ull)bz * sB;

  const int tid  = threadIdx.x;          // 0..511
  const int wave = tid >> 6, lane = tid & 63;

  __shared__ short8 ldsA[2][2048];   // 2 x 32 KB: 8 k8-groups x 256 rows x 16B
  __shared__ short8 ldsB[2][2048];   // 2 x 32 KB

  // Staging: per K-tile, thread owns slots {c*512 + tid}, c=0..3, of A and B.
  // slot s -> k8 = s>>8, row = s&255;  global addr = row*Kd + k8*8 shorts.
  const int rowS = tid & 255;
  const int k8h  = tid >> 8;                        // 0..1
  const short* gA = A  + (long long)(tm * 256 + rowS) * Kd + k8h * 8;
  const short* gB = Bm + (long long)(tn * 256 + rowS) * Kd + k8h * 8;

  floatx4 acc[8][4];
#pragma unroll
  for (int i = 0; i < 8; i++)
#pragma unroll
    for (int j = 0; j < 4; j++) acc[i][j] = (floatx4)(0.0f);

  const int wm = (wave >> 2) * 128;   // wave's M range: 128 rows
  const int wn = (wave & 3) * 64;     // wave's N range: 64 cols
  const int fr = lane & 15;           // fragment row/col select
  const int fq = lane >> 4;           // k8 select within 32-K step

  const int nt = Kd >> 6;

  // Issue one K-tile's staging (8 global_load_lds per wave) into buffer b.
  auto issue = [&](int b) {
    short8* dA = &ldsA[b][tid];
    short8* dB = &ldsB[b][tid];
#pragma unroll
    for (int c = 0; c < 4; c++) glds16(gA + c * 16, dA + c * 512);
#pragma unroll
    for (int c = 0; c < 4; c++) glds16(gB + c * 16, dB + c * 512);
    gA += 64; gB += 64;
  };

  issue(0);
  issue(1);
  VMCNT(8);        // tile 0 landed; tile 1's 8 still in flight
  barrier_raw();

  for (int t = 0; t < nt; t++) {
    const int buf = t & 1;
    const short8* LA = ldsA[buf];
    const short8* LB = ldsB[buf];

    // B fragments for the whole tile, read once (8 x ds_read_b128, 32 VGPR).
    bf16x8 bfr[4][2];
#pragma unroll
    for (int j = 0; j < 4; j++)
#pragma unroll
      for (int ks = 0; ks < 2; ks++)
        bfr[j][ks] = __builtin_bit_cast(
            bf16x8, LB[(fq + 4 * ks) * 256 + wn + j * 16 + fr]);

    // 4 sub-phases: m-quadrant x full-N x K=64 -> 16 MFMA each.
#pragma unroll
    for (int q = 0; q < 4; q++) {
      bf16x8 af[2][2];
#pragma unroll
      for (int i = 0; i < 2; i++)
#pragma unroll
        for (int ks = 0; ks < 2; ks++)
          af[i][ks] = __builtin_bit_cast(
              bf16x8, LA[(fq + 4 * ks) * 256 + wm + (2 * q + i) * 16 + fr]);
      barrier_raw();                       // reads issued; align waves
      __builtin_amdgcn_s_setprio(1);
      __builtin_amdgcn_sched_barrier(0);
#pragma unroll
      for (int ks = 0; ks < 2; ks++)
#pragma unroll
        for (int i = 0; i < 2; i++)
#pragma unroll
          for (int j = 0; j < 4; j++)
            acc[2 * q + i][j] = __builtin_amdgcn_mfma_f32_16x16x32_bf16(
                af[i][ks], bfr[j][ks], acc[2 * q + i][j], 0, 0, 0);
      __builtin_amdgcn_sched_barrier(0);
      __builtin_amdgcn_s_setprio(0);
      barrier_raw();                       // close phase
    }
    // All waves are past every ds_read of buf -> safe to overwrite.
    if (t + 2 < nt)      { issue(buf); VMCNT(8); barrier_raw(); }
    else if (t + 1 < nt) { VMCNT(0);  barrier_raw(); }
  }

  // Epilogue.  C/D layout: col = lane&15, row = (lane>>4)*4 + reg  [m89]
  if (MODE == 3) {
#pragma unroll
    for (int mf = 0; mf < 8; mf++) {
#pragma unroll
      for (int nf = 0; nf < 4; nf++) {
        const int col = tn * 256 + wn + nf * 16 + fr;
#pragma unroll
        for (int r = 0; r < 4; r++) {
          const int row = tm * 256 + wm + mf * 16 + fq * 4 + r;
          float v = acc[mf][nf][r] + bias[col];
          int b = row / Spad;
          int tt = row - b * Spad;
          if (tt >= t_lo && tt < t_hi)
            dst0[((size_t)b * outT + (tt - t_lo)) * DIM + col] = v;
          else if (tt == t_sp)
            dstSp[(size_t)b * DIM + col] = v;
        }
      }
    }
  } else {
    short* C = Cb + (ull)bz * sC;
#pragma unroll
    for (int mf = 0; mf < 8; mf++) {
#pragma unroll
      for (int nf = 0; nf < 4; nf++) {
        const int col = tn * 256 + wn + nf * 16 + fr;
        float bn = (MODE == 1) ? bias[col] : 0.0f;
#pragma unroll
        for (int r = 0; r < 4; r++) {
          const int row = tm * 256 + wm + mf * 16 + fq * 4 + r;
          float v = acc[mf][nf][r] + bn;
          if (MODE == 2) v += bias[row];
          C[(size_t)row * N + col] = f2bf(v);
        }
      }
    }
  }
}

// ---------------------------------------------------------------------------
// In-place row softmax over bf16 score rows. Row length Spad, valid k < S.
// ---------------------------------------------------------------------------
__global__ __launch_bounds__(256)
void softmax_rows(short* __restrict__ SA, int Spad, int S, float scale)
{
  __shared__ float buf[SPMAX];
  __shared__ float red[8];
  const int t = blockIdx.x, b = blockIdx.y;
  short* row = SA + ((size_t)b * Spad + t) * Spad;
  const int tid = threadIdx.x;

  float mx = -1e30f;
  for (int i = tid; i < S; i += 256) {
    float v = bf2f(row[i]) * scale;
    buf[i] = v;
    mx = fmaxf(mx, v);
  }
  for (int off = 32; off; off >>= 1) mx = fmaxf(mx, __shfl_down(mx, off, 64));
  if ((tid & 63) == 0) red[tid >> 6] = mx;
  __syncthreads();
  if (tid == 0) {
    float m = red[0];
    for (int w = 1; w < 4; w++) m = fmaxf(m, red[w]);
    red[0] = m;
  }
  __syncthreads();
  mx = red[0];

  float sum = 0.f;
  for (int i = tid; i < S; i += 256) {
    float e = __expf(buf[i] - mx);
    buf[i] = e;
    sum += e;
  }
  for (int off = 32; off; off >>= 1) sum += __shfl_down(sum, off, 64);
  if ((tid & 63) == 0) red[4 + (tid >> 6)] = sum;
  __syncthreads();
  if (tid == 0) red[4] = 1.0f / (red[4] + red[5] + red[6] + red[7]);
  __syncthreads();
  const float rinv = red[4];

  for (int i = tid; i < S; i += 256) row[i] = f2bf(buf[i] * rinv);
  for (int i = S + tid; i < Spad; i += 256) row[i] = 0;
}

// ---------------------------------------------------------------------------
__global__ __launch_bounds__(256)
void wtrans(const float* __restrict__ W, short* __restrict__ WT)
{
  __shared__ float tile[32][33];
  const int bn = blockIdx.x * 32, bk = blockIdx.y * 32;
  const int tx = threadIdx.x & 31, ty = threadIdx.x >> 5;  // 32 x 8
#pragma unroll
  for (int j = 0; j < 4; j++)
    tile[ty + j * 8][tx] = W[(size_t)(bk + ty + j * 8) * DIM + bn + tx];
  __syncthreads();
#pragma unroll
  for (int j = 0; j < 4; j++)
    WT[(size_t)(bn + ty + j * 8) * DIM + bk + tx] = f2bf(tile[tx][ty + j * 8]);
}

// ---------------------------------------------------------------------------
__global__ __launch_bounds__(256)
void assemble0(const float* __restrict__ seg0, short* __restrict__ X)
{
  const int Spad = SPMAX;
  const int b = blockIdx.y;
  const size_t lin = ((size_t)blockIdx.x * 256 + threadIdx.x) * 4;
  const int t = (int)(lin >> 10), d = (int)(lin & 1023);
  float4 v = make_float4(0.f, 0.f, 0.f, 0.f);
  if (t >= 1 && t <= SEQL)
    v = *(const float4*)(seg0 + ((size_t)b * SEQL + (t - 1)) * DIM + d);
  union { short s[4]; ull u; } o;
  o.s[0] = f2bf(v.x); o.s[1] = f2bf(v.y); o.s[2] = f2bf(v.z); o.s[3] = f2bf(v.w);
  *(ull*)(X + (size_t)b * Spad * DIM + lin) = o.u;
}

__global__ __launch_bounds__(256)
void assembleS(const float* __restrict__ seg1, const float* __restrict__ prompt,
               short* __restrict__ X)
{
  const int Spad = 768;
  const int b = blockIdx.y;
  const size_t lin = ((size_t)blockIdx.x * 256 + threadIdx.x) * 4;
  const int t = (int)(lin >> 10), d = (int)(lin & 1023);
  float4 v = make_float4(0.f, 0.f, 0.f, 0.f);
  if (t == 0 || t == JSUM + 1)
    v = *(const float4*)(prompt + d);
  else if (t >= 1 && t <= JSUM)
    v = *(const float4*)(seg1 + ((size_t)b * SEQL + (t - 1)) * DIM + d);
  union { short s[4]; ull u; } o;
  o.s[0] = f2bf(v.x); o.s[1] = f2bf(v.y); o.s[2] = f2bf(v.z); o.s[3] = f2bf(v.w);
  *(ull*)(X + (size_t)b * Spad * DIM + lin) = o.u;
}

__global__ __launch_bounds__(256)
void assemble1(const float* __restrict__ seg0, const float* __restrict__ seg1,
               const float* __restrict__ P1, short* __restrict__ X)
{
  const int Spad = SPMAX;
  const int b = blockIdx.y;
  const size_t lin = ((size_t)blockIdx.x * 256 + threadIdx.x) * 4;
  const int t = (int)(lin >> 10), d = (int)(lin & 1023);
  float4 v = make_float4(0.f, 0.f, 0.f, 0.f);
  if (t < 32)
    v = *(const float4*)(seg0 + ((size_t)b * SEQL + (SEQL - 32 + t)) * DIM + d);
  else if (t == 32 || t == 2081)
    v = *(const float4*)(P1 + (size_t)b * DIM + d);
  else if (t >= 33 && t <= 2080)
    v = *(const float4*)(seg1 + ((size_t)b * SEQL + (t - 33)) * DIM + d);
  union { short s[4]; ull u; } o;
  o.s[0] = f2bf(v.x); o.s[1] = f2bf(v.y); o.s[2] = f2bf(v.z); o.s[3] = f2bf(v.w);
  *(ull*)(X + (size_t)b * Spad * DIM + lin) = o.u;
}

// ---------------------------------------------------------------------------
__global__ __launch_bounds__(256)
void mem_proj(const float* __restrict__ Sb, const float* __restrict__ M1,
              const float* __restrict__ Wq_mem, const float* __restrict__ bq_mem,
              const float* __restrict__ Wk_mem, const float* __restrict__ bk_mem,
              float* __restrict__ Qn, float* __restrict__ Kp)
{
  const int n = blockIdx.x * 256 + threadIdx.x;
  const int b = blockIdx.y;
  const int w = blockIdx.z;
  const float* x    = w ? M1 : Sb;
  const float* W    = w ? Wk_mem : Wq_mem;
  const float* bias = w ? bk_mem : bq_mem;
  float* o          = w ? Kp : Qn;
  const float* xr = x + (size_t)b * DIM;
  float s = bias[n];
  for (int k = 0; k < DIM; k++) s += xr[k] * W[(size_t)k * DIM + n];
  o[(size_t)b * DIM + n] = s;
}

__global__ __launch_bounds__(256)
void mem_attn(const float* __restrict__ Qn, const float* __restrict__ Kp,
              const float* __restrict__ M1, float* __restrict__ P1, float scale)
{
  __shared__ float red[256];
  __shared__ float w8[8];
  const int b = blockIdx.x, tid = threadIdx.x;
  for (int bp = 0; bp < NBATCH; bp++) {
    float p = 0.f;
    for (int k = tid; k < DIM; k += 256)
      p += Qn[(size_t)b * DIM + k] * Kp[(size_t)bp * DIM + k];
    red[tid] = p; __syncthreads();
    for (int off = 128; off; off >>= 1) {
      if (tid < off) red[tid] += red[tid + off];
      __syncthreads();
    }
    if (tid == 0) w8[bp] = red[0] * scale;
    __syncthreads();
  }
  if (tid == 0) {
    float m = w8[0];
    for (int i = 1; i < NBATCH; i++) m = fmaxf(m, w8[i]);
    float s = 0.f;
    for (int i = 0; i < NBATCH; i++) { w8[i] = __expf(w8[i] - m); s += w8[i]; }
    for (int i = 0; i < NBATCH; i++) w8[i] /= s;
  }
  __syncthreads();
  for (int d = tid; d < DIM; d += 256) {
    float a = 0.f;
    for (int bp = 0; bp < NBATCH; bp++) a += w8[bp] * M1[(size_t)bp * DIM + d];
    P1[(size_t)b * DIM + d] = a;
  }
}

// ---------------------------------------------------------------------------
extern "C" void kernel_launch(void* const* d_in, const int* in_sizes, int n_in,
                              void* d_out, int out_size, void* d_ws, size_t ws_size,
                              hipStream_t stream)
{
  const float* seg0   = (const float*)d_in[0];
  const float* seg1   = (const float*)d_in[1];
  const float* prompt = (const float*)d_in[2];
  const float* Wq_mem = (const float*)d_in[3];
  const float* bq_mem = (const float*)d_in[4];
  const float* Wk_mem = (const float*)d_in[5];
  const float* bk_mem = (const float*)d_in[6];
  const float* Wq     = (const float*)d_in[7];
  const float* bq     = (const float*)d_in[8];
  const float* Wk     = (const float*)d_in[9];
  const float* bk     = (const float*)d_in[10];
  const float* Wv     = (const float*)d_in[11];
  const float* bv     = (const float*)d_in[12];
  const float* Wo     = (const float*)d_in[13];
  const float* bo     = (const float*)d_in[14];
  float* outp = (float*)d_out;

  const size_t WSZ  = (size_t)DIM * DIM * 2;
  const size_t XSZ  = (size_t)NBATCH * SPMAX * DIM * 2;
  const size_t SASZ = (size_t)NBATCH * SPMAX * SPMAX * 2;
  const size_t VSZ  = (size_t)NBATCH * DIM * 4;

  char* p = (char*)d_ws;
  short* WqT = (short*)p; p += WSZ;
  short* WkT = (short*)p; p += WSZ;
  short* WvT = (short*)p; p += WSZ;
  short* WoT = (short*)p; p += WSZ;
  short* X   = (short*)p; p += XSZ;
  short* Qb  = (short*)p; p += XSZ;
  short* Kb  = (short*)p; p += XSZ;
  short* Vt  = (short*)p; p += XSZ;
  short* Ctx = (short*)p; p += XSZ;
  short* SA  = (short*)p; p += SASZ;
  float* M1b = (float*)p; p += VSZ;
  float* Sb  = (float*)p; p += VSZ;
  float* Qn  = (float*)p; p += VSZ;
  float* Kp  = (float*)p; p += VSZ;
  float* P1  = (float*)p; p += VSZ;

  const float scale = 0.03125f;   // 1/sqrt(1024)
  dim3 blk(256, 1, 1);
  dim3 blkG(512, 1, 1);

  auto run_backbone = [&](int Spad, int S,
                          float* o_dst, int t_lo, int t_hi, int outT,
                          float* o_sp, int t_sp) {
    const int MT = NBATCH * Spad / 256;
    // Q = X Wq^T + bq
    gemm_nt<1, false><<<dim3(DIM / 256, MT, 1), blkG, 0, stream>>>(
        X, 0ULL, WqT, 0ULL, Qb, 0ULL, DIM, DIM, bq,
        nullptr, 0, 0, 0, nullptr, -1, Spad);
    // K = X Wk^T + bk
    gemm_nt<1, false><<<dim3(DIM / 256, MT, 1), blkG, 0, stream>>>(
        X, 0ULL, WkT, 0ULL, Kb, 0ULL, DIM, DIM, bk,
        nullptr, 0, 0, 0, nullptr, -1, Spad);
    // Vt[b] (D x Spad) = NT(WvT, X_b) + bv[m]   (batch->XCD swizzle)
    gemm_nt<2, true><<<dim3(Spad / 256, DIM / 256, NBATCH), blkG, 0, stream>>>(
        WvT, 0ULL, X, (ull)Spad * DIM,
        Vt, (ull)DIM * Spad, Spad, DIM, bv,
        nullptr, 0, 0, 0, nullptr, -1, Spad);
    // scores[b] = Q_b K_b^T   (batch->XCD swizzle)
    gemm_nt<0, true><<<dim3(Spad / 256, Spad / 256, NBATCH), blkG, 0, stream>>>(
        Qb, (ull)Spad * DIM, Kb, (ull)Spad * DIM,
        SA, (ull)Spad * Spad, Spad, DIM, nullptr,
        nullptr, 0, 0, 0, nullptr, -1, Spad);
    softmax_rows<<<dim3(Spad, NBATCH), blk, 0, stream>>>(SA, Spad, S, scale);
    // ctx[b] = attn_b Vt_b^T   (batch->XCD swizzle)
    gemm_nt<0, true><<<dim3(DIM / 256, Spad / 256, NBATCH), blkG, 0, stream>>>(
        SA, (ull)Spad * Spad, Vt, (ull)DIM * Spad,
        Ctx, (ull)Spad * DIM, DIM, Spad, nullptr,
        nullptr, 0, 0, 0, nullptr, -1, Spad);
    // H = ctx Wo^T + bo, scattered to outputs
    gemm_nt<3, false><<<dim3(DIM / 256, MT, 1), blkG, 0, stream>>>(
        Ctx, 0ULL, WoT, 0ULL, nullptr, 0ULL, DIM, DIM, bo,
        o_dst, t_lo, t_hi, outT, o_sp, t_sp, Spad);
  };

  wtrans<<<dim3(32, 32), blk, 0, stream>>>(Wq, WqT);
  wtrans<<<dim3(32, 32), blk, 0, stream>>>(Wk, WkT);
  wtrans<<<dim3(32, 32), blk, 0, stream>>>(Wv, WvT);
  wtrans<<<dim3(32, 32), blk, 0, stream>>>(Wo, WoT);

  // Phase 0: backbone([P0, seg0, P0])  S=2050, Spad=2304
  assemble0<<<dim3(SPMAX, NBATCH), blk, 0, stream>>>(seg0, X);
  run_backbone(SPMAX, 2050, outp, 33, 2049, 2016, M1b, 2049);

  // Phase S: summarize(seg1)  S=514, Spad=768
  assembleS<<<dim3(768, NBATCH), blk, 0, stream>>>(seg1, prompt, X);
  run_backbone(768, 514, nullptr, 0, 0, 0, Sb, JSUM);

  // Memory attention (exact f32)
  mem_proj<<<dim3(DIM / 256, NBATCH, 2), blk, 0, stream>>>(
      Sb, M1b, Wq_mem, bq_mem, Wk_mem, bk_mem, Qn, Kp);
  mem_attn<<<dim3(NBATCH), blk, 0, stream>>>(Qn, Kp, M1b, P1, scale);

  // Phase 1: backbone([seg0[-32:], P1, seg1, P1])  S=2082, Spad=2304
  assemble1<<<dim3(SPMAX, NBATCH), blk, 0, stream>>>(seg0, seg1, P1, X);
  run_backbone(SPMAX, 2082, outp + (size_t)NBATCH * 2016 * DIM,
               33, 2081, 2048, nullptr, -1);
}

// Round 2
// 1925.582 us; speedup vs baseline: 1.3399x; 1.3399x over previous
//
#include <hip/hip_runtime.h>
#include <stdint.h>
#include <stddef.h>

#define DIM    1024
#define NBATCH 8
#define SEQL   2048
#define JSUM   512

typedef unsigned long long ull;
typedef __attribute__((ext_vector_type(8))) __bf16 bf16x8;
typedef __attribute__((ext_vector_type(8))) short  short8;
typedef __attribute__((ext_vector_type(4))) float  floatx4;

__device__ __forceinline__ short f2bf(float f) {
  unsigned u = __builtin_bit_cast(unsigned, f);
  u = (u + 0x7fffu + ((u >> 16) & 1u)) >> 16;   // RNE
  return (short)u;
}
__device__ __forceinline__ float bf2f(short s) {
  unsigned u = ((unsigned)(unsigned short)s) << 16;
  return __builtin_bit_cast(float, u);
}

// NOTE: the intrinsic's imm-offset arg applies to BOTH global and LDS
// addresses — always pass 0 and do pointer arithmetic on both sides.
__device__ __forceinline__ void glds16(const short* g, short8* l) {
  __builtin_amdgcn_global_load_lds(
      (const __attribute__((address_space(1))) unsigned int*)g,
      (__attribute__((address_space(3))) unsigned int*)l, 16, 0, 0);
}

// Counted vmcnt wait (T4): never drain to 0 inside the K-loop.
#define VMCNT(n) do { asm volatile("s_waitcnt vmcnt(" #n ")" ::: "memory"); \
                      __builtin_amdgcn_sched_barrier(0); } while (0)

// Raw barrier WITHOUT the implicit s_waitcnt vmcnt(0) of __syncthreads().
// Safe here because (a) every ds_read's consuming MFMA precedes the barrier
// (data dep forces lgkmcnt drain), (b) cross-wave LDS visibility of staged
// tiles is established by per-wave VMCNT(N) + this barrier.
__device__ __forceinline__ void barrier_raw() {
  asm volatile("" ::: "memory");
  __builtin_amdgcn_s_barrier();
  asm volatile("" ::: "memory");
}

// ---------------------------------------------------------------------------
// NT GEMM: C[m,n] = sum_k A[m,k]*B[n,k]. A: M x K row-major, B: N x K row-major.
// 128x128 tile, BK=64, 256 threads (4 waves, 2x2), double-buffered LDS
// (2 x 32 KiB = 64 KiB -> 2 blocks/CU) with counted-vmcnt pipeline:
// loads for tile t+2 issue at the end of tile t; the loop waits vmcnt(8)
// (tile t+1's loads, issued one full K-step earlier), never vmcnt(0).
// Requires K % 64 == 0 and K >= 128 (prologue stages 2 tiles).
// MODE 0: C bf16            MODE 1: C bf16 + bias[n]
// MODE 2: C bf16 + bias[m]  MODE 3: f32 scatter rows (+bias[n])
// SWIZ 0: tn=bx, tm=by, bz=blockIdx.z
// SWIZ 1: gridDim.z==8; batch = lin&7 pins batch->XCD, tiles contiguous/XCD
// SWIZ 2: tm=bx, tn=by, bz=0 — co-locates the gridDim.y N-tiles sharing an
//         A-panel on one XCD when gridDim.x % 8 == 0 (lin%8 == bx%8).
// LDS fragment-major: 16B block (k8,row) at k8*128+row; BK=64 -> k8 in 0..7.
// Measured conflict-free (SQ_LDS_BANK_CONFLICT = 0).
// ---------------------------------------------------------------------------
template<int MODE, int SWIZ>
__global__ __launch_bounds__(256)
void gemm_nt(const short* __restrict__ A, ull sA,
             const short* __restrict__ Bm, ull sB,
             short* __restrict__ Cb, ull sC,
             int N, int Kd,
             const float* __restrict__ bias,
             float* __restrict__ dst0, int t_lo, int t_hi, int outT,
             float* __restrict__ dstSp, int t_sp, int Spad)
{
  int tn, tm, bz;
  if (SWIZ == 1) {
    const unsigned gx = gridDim.x;
    ull lin = blockIdx.x + (ull)gx * (blockIdx.y + (ull)gridDim.y * blockIdx.z);
    bz = (int)(lin & 7);
    ull s = lin >> 3;
    tn = (int)(s % gx);
    tm = (int)(s / gx);
  } else if (SWIZ == 2) {
    tm = blockIdx.x; tn = blockIdx.y; bz = 0;
  } else {
    tn = blockIdx.x; tm = blockIdx.y; bz = blockIdx.z;
  }

  A  += (ull)bz * sA;
  Bm += (ull)bz * sB;

  const int tid  = threadIdx.x;
  const int wave = tid >> 6, lane = tid & 63;

  __shared__ short8 ldsA[2][1024];   // 2 x 16 KB: 8 k8-groups x 128 rows x 16B
  __shared__ short8 ldsB[2][1024];   // 2 x 16 KB

  // Staging: thread tid owns blocks {tid + 256c}, c=0..3, of each tile.
  const int r0  = tid & 127;
  const int k80 = tid >> 7;                         // 0..1
  const short* gA = A  + (long long)(tm * 128 + r0) * Kd + k80 * 8;
  const short* gB = Bm + (long long)(tn * 128 + r0) * Kd + k80 * 8;

  floatx4 acc[4][4];
#pragma unroll
  for (int i = 0; i < 4; i++)
#pragma unroll
    for (int j = 0; j < 4; j++) acc[i][j] = (floatx4)(0.0f);

  const int wm = (wave >> 1) * 64;
  const int wn = (wave & 1) * 64;
  const int fr = lane & 15;      // fragment row/col select
  const int fq = lane >> 4;      // k8 select within 32-K half

  const int nt = Kd >> 6;

  // Issue one K-tile's staging (8 global_load_lds per wave) into buffer b.
  auto issue = [&](int b) {
    short8* dA = &ldsA[b][wave * 64];
    short8* dB = &ldsB[b][wave * 64];
#pragma unroll
    for (int c = 0; c < 4; c++) glds16(gA + c * 16, dA + c * 256);
#pragma unroll
    for (int c = 0; c < 4; c++) glds16(gB + c * 16, dB + c * 256);
    gA += 64; gB += 64;
  };

  issue(0);            // 8 outstanding
  issue(1);            // 16 outstanding
  VMCNT(8);            // tile 0 landed (tile 1's 8 still in flight)
  barrier_raw();

  for (int t = 0; t < nt; t++) {
    const int buf = t & 1;
    const short8* LA = ldsA[buf];
    const short8* LB = ldsB[buf];

#pragma unroll
    for (int h = 0; h < 2; h++) {
      bf16x8 af[4], bv4[4];
      const int aoff = (fq + 4 * h) * 128 + wm + fr;
      const int boff = (fq + 4 * h) * 128 + wn + fr;
#pragma unroll
      for (int mt = 0; mt < 4; mt++)
        af[mt] = __builtin_bit_cast(bf16x8, LA[aoff + mt * 16]);
#pragma unroll
      for (int nt2 = 0; nt2 < 4; nt2++)
        bv4[nt2] = __builtin_bit_cast(bf16x8, LB[boff + nt2 * 16]);
#pragma unroll
      for (int mt = 0; mt < 4; mt++)
#pragma unroll
        for (int nt2 = 0; nt2 < 4; nt2++)
          acc[mt][nt2] = __builtin_amdgcn_mfma_f32_16x16x32_bf16(
              af[mt], bv4[nt2], acc[mt][nt2], 0, 0, 0);
    }

    barrier_raw();     // every wave is done READING buf -> safe to overwrite
    if (t + 2 < nt)      { issue(buf); VMCNT(8); }  // wait = t+1's loads only
    else if (t + 1 < nt) { VMCNT(0); }              // drain final tile
    barrier_raw();     // tile t+1 visible to all waves
  }

  // Epilogue.  C/D layout: col = lane&15, row = (lane>>4)*4 + reg  [m89]
  if (MODE == 3) {
#pragma unroll
    for (int mt = 0; mt < 4; mt++) {
#pragma unroll
      for (int nt2 = 0; nt2 < 4; nt2++) {
        const int col = tn * 128 + wn + nt2 * 16 + fr;
#pragma unroll
        for (int r = 0; r < 4; r++) {
          const int row = tm * 128 + wm + mt * 16 + fq * 4 + r;
          float v = acc[mt][nt2][r] + bias[col];
          int b = row / Spad;
          int tt = row - b * Spad;
          if (tt >= t_lo && tt < t_hi)
            dst0[((size_t)b * outT + (tt - t_lo)) * DIM + col] = v;
          else if (tt == t_sp)
            dstSp[(size_t)b * DIM + col] = v;
        }
      }
    }
  } else {
    short* C = Cb + (ull)bz * sC;
#pragma unroll
    for (int mt = 0; mt < 4; mt++) {
#pragma unroll
      for (int nt2 = 0; nt2 < 4; nt2++) {
        const int col = tn * 128 + wn + nt2 * 16 + fr;
        float bn = (MODE == 1) ? bias[col] : 0.0f;
#pragma unroll
        for (int r = 0; r < 4; r++) {
          const int row = tm * 128 + wm + mt * 16 + fq * 4 + r;
          float v = acc[mt][nt2][r] + bn;
          if (MODE == 2) v += bias[row];
          C[(size_t)row * N + col] = f2bf(v);
        }
      }
    }
  }
}

// ---------------------------------------------------------------------------
// In-place row softmax over bf16 score rows. Row length Spad, valid k < S.
// ---------------------------------------------------------------------------
__global__ __launch_bounds__(256)
void softmax_rows(short* __restrict__ SA, int Spad, int S, float scale)
{
  __shared__ float buf[2176];
  __shared__ float red[8];
  const int t = blockIdx.x, b = blockIdx.y;
  short* row = SA + ((size_t)b * Spad + t) * Spad;
  const int tid = threadIdx.x;

  float mx = -1e30f;
  for (int i = tid; i < S; i += 256) {
    float v = bf2f(row[i]) * scale;
    buf[i] = v;
    mx = fmaxf(mx, v);
  }
  for (int off = 32; off; off >>= 1) mx = fmaxf(mx, __shfl_down(mx, off, 64));
  if ((tid & 63) == 0) red[tid >> 6] = mx;
  __syncthreads();
  if (tid == 0) {
    float m = red[0];
    for (int w = 1; w < 4; w++) m = fmaxf(m, red[w]);
    red[0] = m;
  }
  __syncthreads();
  mx = red[0];

  float sum = 0.f;
  for (int i = tid; i < S; i += 256) {
    float e = __expf(buf[i] - mx);
    buf[i] = e;
    sum += e;
  }
  for (int off = 32; off; off >>= 1) sum += __shfl_down(sum, off, 64);
  if ((tid & 63) == 0) red[4 + (tid >> 6)] = sum;
  __syncthreads();
  if (tid == 0) red[4] = 1.0f / (red[4] + red[5] + red[6] + red[7]);
  __syncthreads();
  const float rinv = red[4];

  for (int i = tid; i < S; i += 256) row[i] = f2bf(buf[i] * rinv);
  for (int i = S + tid; i < Spad; i += 256) row[i] = 0;
}

// ---------------------------------------------------------------------------
__global__ __launch_bounds__(256)
void wtrans(const float* __restrict__ W, short* __restrict__ WT)
{
  __shared__ float tile[32][33];
  const int bn = blockIdx.x * 32, bk = blockIdx.y * 32;
  const int tx = threadIdx.x & 31, ty = threadIdx.x >> 5;  // 32 x 8
#pragma unroll
  for (int j = 0; j < 4; j++)
    tile[ty + j * 8][tx] = W[(size_t)(bk + ty + j * 8) * DIM + bn + tx];
  __syncthreads();
#pragma unroll
  for (int j = 0; j < 4; j++)
    WT[(size_t)(bn + ty + j * 8) * DIM + bk + tx] = f2bf(tile[tx][ty + j * 8]);
}

// ---------------------------------------------------------------------------
__global__ __launch_bounds__(256)
void assemble0(const float* __restrict__ seg0, short* __restrict__ X)
{
  const int Spad = 2176;
  const int b = blockIdx.y;
  const size_t lin = ((size_t)blockIdx.x * 256 + threadIdx.x) * 4;
  const int t = (int)(lin >> 10), d = (int)(lin & 1023);
  float4 v = make_float4(0.f, 0.f, 0.f, 0.f);
  if (t >= 1 && t <= SEQL)
    v = *(const float4*)(seg0 + ((size_t)b * SEQL + (t - 1)) * DIM + d);
  union { short s[4]; ull u; } o;
  o.s[0] = f2bf(v.x); o.s[1] = f2bf(v.y); o.s[2] = f2bf(v.z); o.s[3] = f2bf(v.w);
  *(ull*)(X + (size_t)b * Spad * DIM + lin) = o.u;
}

__global__ __launch_bounds__(256)
void assembleS(const float* __restrict__ seg1, const float* __restrict__ prompt,
               short* __restrict__ X)
{
  const int Spad = 640;
  const int b = blockIdx.y;
  const size_t lin = ((size_t)blockIdx.x * 256 + threadIdx.x) * 4;
  const int t = (int)(lin >> 10), d = (int)(lin & 1023);
  float4 v = make_float4(0.f, 0.f, 0.f, 0.f);
  if (t == 0 || t == JSUM + 1)
    v = *(const float4*)(prompt + d);
  else if (t >= 1 && t <= JSUM)
    v = *(const float4*)(seg1 + ((size_t)b * SEQL + (t - 1)) * DIM + d);
  union { short s[4]; ull u; } o;
  o.s[0] = f2bf(v.x); o.s[1] = f2bf(v.y); o.s[2] = f2bf(v.z); o.s[3] = f2bf(v.w);
  *(ull*)(X + (size_t)b * Spad * DIM + lin) = o.u;
}

__global__ __launch_bounds__(256)
void assemble1(const float* __restrict__ seg0, const float* __restrict__ seg1,
               const float* __restrict__ P1, short* __restrict__ X)
{
  const int Spad = 2176;
  const int b = blockIdx.y;
  const size_t lin = ((size_t)blockIdx.x * 256 + threadIdx.x) * 4;
  const int t = (int)(lin >> 10), d = (int)(lin & 1023);
  float4 v = make_float4(0.f, 0.f, 0.f, 0.f);
  if (t < 32)
    v = *(const float4*)(seg0 + ((size_t)b * SEQL + (SEQL - 32 + t)) * DIM + d);
  else if (t == 32 || t == 2081)
    v = *(const float4*)(P1 + (size_t)b * DIM + d);
  else if (t >= 33 && t <= 2080)
    v = *(const float4*)(seg1 + ((size_t)b * SEQL + (t - 33)) * DIM + d);
  union { short s[4]; ull u; } o;
  o.s[0] = f2bf(v.x); o.s[1] = f2bf(v.y); o.s[2] = f2bf(v.z); o.s[3] = f2bf(v.w);
  *(ull*)(X + (size_t)b * Spad * DIM + lin) = o.u;
}

// ---------------------------------------------------------------------------
__global__ __launch_bounds__(256)
void mem_proj(const float* __restrict__ Sb, const float* __restrict__ M1,
              const float* __restrict__ Wq_mem, const float* __restrict__ bq_mem,
              const float* __restrict__ Wk_mem, const float* __restrict__ bk_mem,
              float* __restrict__ Qn, float* __restrict__ Kp)
{
  const int n = blockIdx.x * 256 + threadIdx.x;
  const int b = blockIdx.y;
  const int w = blockIdx.z;
  const float* x    = w ? M1 : Sb;
  const float* W    = w ? Wk_mem : Wq_mem;
  const float* bias = w ? bk_mem : bq_mem;
  float* o          = w ? Kp : Qn;
  const float* xr = x + (size_t)b * DIM;
  float s = bias[n];
  for (int k = 0; k < DIM; k++) s += xr[k] * W[(size_t)k * DIM + n];
  o[(size_t)b * DIM + n] = s;
}

__global__ __launch_bounds__(256)
void mem_attn(const float* __restrict__ Qn, const float* __restrict__ Kp,
              const float* __restrict__ M1, float* __restrict__ P1, float scale)
{
  __shared__ float red[256];
  __shared__ float w8[8];
  const int b = blockIdx.x, tid = threadIdx.x;
  for (int bp = 0; bp < NBATCH; bp++) {
    float p = 0.f;
    for (int k = tid; k < DIM; k += 256)
      p += Qn[(size_t)b * DIM + k] * Kp[(size_t)bp * DIM + k];
    red[tid] = p; __syncthreads();
    for (int off = 128; off; off >>= 1) {
      if (tid < off) red[tid] += red[tid + off];
      __syncthreads();
    }
    if (tid == 0) w8[bp] = red[0] * scale;
    __syncthreads();
  }
  if (tid == 0) {
    float m = w8[0];
    for (int i = 1; i < NBATCH; i++) m = fmaxf(m, w8[i]);
    float s = 0.f;
    for (int i = 0; i < NBATCH; i++) { w8[i] = __expf(w8[i] - m); s += w8[i]; }
    for (int i = 0; i < NBATCH; i++) w8[i] /= s;
  }
  __syncthreads();
  for (int d = tid; d < DIM; d += 256) {
    float a = 0.f;
    for (int bp = 0; bp < NBATCH; bp++) a += w8[bp] * M1[(size_t)bp * DIM + d];
    P1[(size_t)b * DIM + d] = a;
  }
}

// ---------------------------------------------------------------------------
extern "C" void kernel_launch(void* const* d_in, const int* in_sizes, int n_in,
                              void* d_out, int out_size, void* d_ws, size_t ws_size,
                              hipStream_t stream)
{
  const float* seg0   = (const float*)d_in[0];
  const float* seg1   = (const float*)d_in[1];
  const float* prompt = (const float*)d_in[2];
  const float* Wq_mem = (const float*)d_in[3];
  const float* bq_mem = (const float*)d_in[4];
  const float* Wk_mem = (const float*)d_in[5];
  const float* bk_mem = (const float*)d_in[6];
  const float* Wq     = (const float*)d_in[7];
  const float* bq     = (const float*)d_in[8];
  const float* Wk     = (const float*)d_in[9];
  const float* bk     = (const float*)d_in[10];
  const float* Wv     = (const float*)d_in[11];
  const float* bv     = (const float*)d_in[12];
  const float* Wo     = (const float*)d_in[13];
  const float* bo     = (const float*)d_in[14];
  float* outp = (float*)d_out;

  const int   SPMAX = 2176;
  const size_t WSZ  = (size_t)DIM * DIM * 2;
  const size_t XSZ  = (size_t)NBATCH * SPMAX * DIM * 2;
  const size_t SASZ = (size_t)NBATCH * SPMAX * SPMAX * 2;
  const size_t VSZ  = (size_t)NBATCH * DIM * 4;

  char* p = (char*)d_ws;
  short* WqT = (short*)p; p += WSZ;
  short* WkT = (short*)p; p += WSZ;
  short* WvT = (short*)p; p += WSZ;
  short* WoT = (short*)p; p += WSZ;
  short* X   = (short*)p; p += XSZ;
  short* Qb  = (short*)p; p += XSZ;
  short* Kb  = (short*)p; p += XSZ;
  short* Vt  = (short*)p; p += XSZ;
  short* Ctx = (short*)p; p += XSZ;
  short* SA  = (short*)p; p += SASZ;
  float* M1b = (float*)p; p += VSZ;
  float* Sb  = (float*)p; p += VSZ;
  float* Qn  = (float*)p; p += VSZ;
  float* Kp  = (float*)p; p += VSZ;
  float* P1  = (float*)p; p += VSZ;

  const float scale = 0.03125f;   // 1/sqrt(1024)
  dim3 blk(256, 1, 1);

  auto run_backbone = [&](int Spad, int S,
                          float* o_dst, int t_lo, int t_hi, int outT,
                          float* o_sp, int t_sp) {
    const int MT = NBATCH * Spad / 128;
    // Q = X Wq^T + bq   (SWIZ=2: A-panel sharers on one XCD; MT % 8 == 0)
    gemm_nt<1, 2><<<dim3(MT, DIM / 128, 1), blk, 0, stream>>>(
        X, 0ULL, WqT, 0ULL, Qb, 0ULL, DIM, DIM, bq,
        nullptr, 0, 0, 0, nullptr, -1, Spad);
    // K = X Wk^T + bk
    gemm_nt<1, 2><<<dim3(MT, DIM / 128, 1), blk, 0, stream>>>(
        X, 0ULL, WkT, 0ULL, Kb, 0ULL, DIM, DIM, bk,
        nullptr, 0, 0, 0, nullptr, -1, Spad);
    // Vt[b] (D x Spad) = NT(WvT, X_b) + bv[m]   (batch->XCD swizzle)
    gemm_nt<2, 1><<<dim3(Spad / 128, DIM / 128, NBATCH), blk, 0, stream>>>(
        WvT, 0ULL, X, (ull)Spad * DIM,
        Vt, (ull)DIM * Spad, Spad, DIM, bv,
        nullptr, 0, 0, 0, nullptr, -1, Spad);
    // scores[b] = Q_b K_b^T   (batch->XCD swizzle)
    gemm_nt<0, 1><<<dim3(Spad / 128, Spad / 128, NBATCH), blk, 0, stream>>>(
        Qb, (ull)Spad * DIM, Kb, (ull)Spad * DIM,
        SA, (ull)Spad * Spad, Spad, DIM, nullptr,
        nullptr, 0, 0, 0, nullptr, -1, Spad);
    softmax_rows<<<dim3(Spad, NBATCH), blk, 0, stream>>>(SA, Spad, S, scale);
    // ctx[b] = attn_b Vt_b^T   (batch->XCD swizzle)
    gemm_nt<0, 1><<<dim3(DIM / 128, Spad / 128, NBATCH), blk, 0, stream>>>(
        SA, (ull)Spad * Spad, Vt, (ull)DIM * Spad,
        Ctx, (ull)Spad * DIM, DIM, Spad, nullptr,
        nullptr, 0, 0, 0, nullptr, -1, Spad);
    // H = ctx Wo^T + bo, scattered to outputs
    gemm_nt<3, 2><<<dim3(MT, DIM / 128, 1), blk, 0, stream>>>(
        Ctx, 0ULL, WoT, 0ULL, nullptr, 0ULL, DIM, DIM, bo,
        o_dst, t_lo, t_hi, outT, o_sp, t_sp, Spad);
  };

  wtrans<<<dim3(32, 32), blk, 0, stream>>>(Wq, WqT);
  wtrans<<<dim3(32, 32), blk, 0, stream>>>(Wk, WkT);
  wtrans<<<dim3(32, 32), blk, 0, stream>>>(Wv, WvT);
  wtrans<<<dim3(32, 32), blk, 0, stream>>>(Wo, WoT);

  // Phase 0: backbone([P0, seg0, P0])  S=2050, Spad=2176
  assemble0<<<dim3(2176, NBATCH), blk, 0, stream>>>(seg0, X);
  run_backbone(2176, 2050, outp, 33, 2049, 2016, M1b, 2049);

  // Phase S: summarize(seg1)  S=514, Spad=640
  assembleS<<<dim3(640, NBATCH), blk, 0, stream>>>(seg1, prompt, X);
  run_backbone(640, 514, nullptr, 0, 0, 0, Sb, JSUM);

  // Memory attention (exact f32)
  mem_proj<<<dim3(DIM / 256, NBATCH, 2), blk, 0, stream>>>(
      Sb, M1b, Wq_mem, bq_mem, Wk_mem, bk_mem, Qn, Kp);
  mem_attn<<<dim3(NBATCH), blk, 0, stream>>>(Qn, Kp, M1b, P1, scale);

  // Phase 1: backbone([seg0[-32:], P1, seg1, P1])  S=2082, Spad=2176
  assemble1<<<dim3(2176, NBATCH), blk, 0, stream>>>(seg0, seg1, P1, X);
  run_backbone(2176, 2082, outp + (size_t)NBATCH * 2016 * DIM,
               33, 2081, 2048, nullptr, -1);
}

// Round 3
// 1817.434 us; speedup vs baseline: 1.4196x; 1.0595x over previous
//
#include <hip/hip_runtime.h>
#include <stdint.h>
#include <stddef.h>

#define DIM    1024
#define NBATCH 8
#define SEQL   2048
#define JSUM   512

typedef unsigned long long ull;
typedef __attribute__((ext_vector_type(8))) __bf16 bf16x8;
typedef __attribute__((ext_vector_type(8))) short  short8;
typedef __attribute__((ext_vector_type(4))) float  floatx4;

__device__ __forceinline__ short f2bf(float f) {
  unsigned u = __builtin_bit_cast(unsigned, f);
  u = (u + 0x7fffu + ((u >> 16) & 1u)) >> 16;   // RNE
  return (short)u;
}
__device__ __forceinline__ float bf2f(short s) {
  unsigned u = ((unsigned)(unsigned short)s) << 16;
  return __builtin_bit_cast(float, u);
}

// NOTE: the intrinsic's imm-offset arg applies to BOTH global and LDS
// addresses — always pass 0 and do pointer arithmetic on both sides.
__device__ __forceinline__ void glds16(const short* g, short8* l) {
  __builtin_amdgcn_global_load_lds(
      (const __attribute__((address_space(1))) unsigned int*)g,
      (__attribute__((address_space(3))) unsigned int*)l, 16, 0, 0);
}

// Counted vmcnt wait (T4): never drain to 0 inside the K-loop.
#define VMCNT(n) do { asm volatile("s_waitcnt vmcnt(" #n ")" ::: "memory"); \
                      __builtin_amdgcn_sched_barrier(0); } while (0)

// Raw barrier WITHOUT the implicit s_waitcnt vmcnt(0) of __syncthreads().
// Safe because (a) every ds_read's consuming MFMA precedes the barrier
// (data dep forces lgkmcnt drain), (b) cross-wave LDS visibility of staged
// tiles is established by per-wave VMCNT(N) + this barrier.
__device__ __forceinline__ void barrier_raw() {
  asm volatile("" ::: "memory");
  __builtin_amdgcn_s_barrier();
  asm volatile("" ::: "memory");
}

// ---------------------------------------------------------------------------
// NT GEMM: C[m,n] = sum_k A[m,k]*B[n,k]. A: M x K row-major, B: N x K row-major.
// 128x128 tile, BK=32, 256 threads (4 waves, 2x2), double-buffered LDS
// (2 x 16 KiB = 32 KiB -> up to 5 blocks/CU) with counted-vmcnt pipeline:
// loads for tile t+2 issue at the end of tile t; the loop waits vmcnt(4)
// (tile t+1's loads, issued one full K-step earlier), never vmcnt(0).
// Rationale (R0-R2 counters): perf tracks blocks/CU (m114 cross-block
// overlap fills the per-block latency gap); this keeps R2's pipeline at
// R0's 32 KiB LDS footprint.
// Requires K % 32 == 0 and K >= 64 (prologue stages 2 tiles).
// MODE 0: C bf16            MODE 1: C bf16 + bias[n]
// MODE 2: C bf16 + bias[m]  MODE 3: f32 scatter rows (+bias[n])
// SWIZ 0: tn=bx, tm=by, bz=blockIdx.z
// SWIZ 1: gridDim.z==8; batch = lin&7 pins batch->XCD, tiles contiguous/XCD
// SWIZ 2: tm=bx, tn=by, bz=0 — co-locates the gridDim.y N-tiles sharing an
//         A-panel on one XCD when gridDim.x % 8 == 0 (lin%8 == bx%8).
// LDS fragment-major: 16B block (k8,row) at k8*128+row; BK=32 -> k8 in 0..3.
// Measured conflict-free (SQ_LDS_BANK_CONFLICT = 0).
// ---------------------------------------------------------------------------
template<int MODE, int SWIZ>
__global__ __launch_bounds__(256)
void gemm_nt(const short* __restrict__ A, ull sA,
             const short* __restrict__ Bm, ull sB,
             short* __restrict__ Cb, ull sC,
             int N, int Kd,
             const float* __restrict__ bias,
             float* __restrict__ dst0, int t_lo, int t_hi, int outT,
             float* __restrict__ dstSp, int t_sp, int Spad)
{
  int tn, tm, bz;
  if (SWIZ == 1) {
    const unsigned gx = gridDim.x;
    ull lin = blockIdx.x + (ull)gx * (blockIdx.y + (ull)gridDim.y * blockIdx.z);
    bz = (int)(lin & 7);
    ull s = lin >> 3;
    tn = (int)(s % gx);
    tm = (int)(s / gx);
  } else if (SWIZ == 2) {
    tm = blockIdx.x; tn = blockIdx.y; bz = 0;
  } else {
    tn = blockIdx.x; tm = blockIdx.y; bz = blockIdx.z;
  }

  A  += (ull)bz * sA;
  Bm += (ull)bz * sB;

  const int tid  = threadIdx.x;
  const int wave = tid >> 6, lane = tid & 63;

  __shared__ short8 ldsA[2][512];   // 2 x 8 KB: 4 k8-groups x 128 rows x 16B
  __shared__ short8 ldsB[2][512];   // 2 x 8 KB

  // Staging: thread tid owns slots {tid + 256c}, c=0..1, of each tile.
  // slot s -> k8 = s>>7 (0..3), row = s&127.
  const int r0  = tid & 127;
  const int k80 = tid >> 7;                         // 0..1
  const short* gA = A  + (long long)(tm * 128 + r0) * Kd + k80 * 8;
  const short* gB = Bm + (long long)(tn * 128 + r0) * Kd + k80 * 8;

  floatx4 acc[4][4];
#pragma unroll
  for (int i = 0; i < 4; i++)
#pragma unroll
    for (int j = 0; j < 4; j++) acc[i][j] = (floatx4)(0.0f);

  const int wm = (wave >> 1) * 64;
  const int wn = (wave & 1) * 64;
  const int fr = lane & 15;      // fragment row/col select
  const int fq = lane >> 4;      // k8 select (0..3) within the 32-K tile

  const int nt = Kd >> 5;

  // Issue one K-tile's staging (4 global_load_lds per wave) into buffer b.
  auto issue = [&](int b) {
    short8* dA = &ldsA[b][wave * 64];
    short8* dB = &ldsB[b][wave * 64];
#pragma unroll
    for (int c = 0; c < 2; c++) glds16(gA + c * 16, dA + c * 256);
#pragma unroll
    for (int c = 0; c < 2; c++) glds16(gB + c * 16, dB + c * 256);
    gA += 32; gB += 32;
  };

  issue(0);            // 4 outstanding
  issue(1);            // 8 outstanding
  VMCNT(4);            // tile 0 landed (tile 1's 4 still in flight)
  barrier_raw();

  for (int t = 0; t < nt; t++) {
    const int buf = t & 1;
    const short8* LA = ldsA[buf];
    const short8* LB = ldsB[buf];

    bf16x8 af[4], bv4[4];
    const int aoff = fq * 128 + wm + fr;
    const int boff = fq * 128 + wn + fr;
#pragma unroll
    for (int mt = 0; mt < 4; mt++)
      af[mt] = __builtin_bit_cast(bf16x8, LA[aoff + mt * 16]);
#pragma unroll
    for (int nt2 = 0; nt2 < 4; nt2++)
      bv4[nt2] = __builtin_bit_cast(bf16x8, LB[boff + nt2 * 16]);
#pragma unroll
    for (int mt = 0; mt < 4; mt++)
#pragma unroll
      for (int nt2 = 0; nt2 < 4; nt2++)
        acc[mt][nt2] = __builtin_amdgcn_mfma_f32_16x16x32_bf16(
            af[mt], bv4[nt2], acc[mt][nt2], 0, 0, 0);

    barrier_raw();     // every wave is done READING buf -> safe to overwrite
    if (t + 2 < nt)      { issue(buf); VMCNT(4); }  // wait = t+1's loads only
    else if (t + 1 < nt) { VMCNT(0); }              // drain final tile
    barrier_raw();     // tile t+1 visible to all waves
  }

  // Epilogue.  C/D layout: col = lane&15, row = (lane>>4)*4 + reg  [m89]
  if (MODE == 3) {
#pragma unroll
    for (int mt = 0; mt < 4; mt++) {
#pragma unroll
      for (int nt2 = 0; nt2 < 4; nt2++) {
        const int col = tn * 128 + wn + nt2 * 16 + fr;
#pragma unroll
        for (int r = 0; r < 4; r++) {
          const int row = tm * 128 + wm + mt * 16 + fq * 4 + r;
          float v = acc[mt][nt2][r] + bias[col];
          int b = row / Spad;
          int tt = row - b * Spad;
          if (tt >= t_lo && tt < t_hi)
            dst0[((size_t)b * outT + (tt - t_lo)) * DIM + col] = v;
          else if (tt == t_sp)
            dstSp[(size_t)b * DIM + col] = v;
        }
      }
    }
  } else {
    short* C = Cb + (ull)bz * sC;
#pragma unroll
    for (int mt = 0; mt < 4; mt++) {
#pragma unroll
      for (int nt2 = 0; nt2 < 4; nt2++) {
        const int col = tn * 128 + wn + nt2 * 16 + fr;
        float bn = (MODE == 1) ? bias[col] : 0.0f;
#pragma unroll
        for (int r = 0; r < 4; r++) {
          const int row = tm * 128 + wm + mt * 16 + fq * 4 + r;
          float v = acc[mt][nt2][r] + bn;
          if (MODE == 2) v += bias[row];
          C[(size_t)row * N + col] = f2bf(v);
        }
      }
    }
  }
}

// ---------------------------------------------------------------------------
// In-place row softmax over bf16 score rows. Row length Spad, valid k < S.
// ---------------------------------------------------------------------------
__global__ __launch_bounds__(256)
void softmax_rows(short* __restrict__ SA, int Spad, int S, float scale)
{
  __shared__ float buf[2176];
  __shared__ float red[8];
  const int t = blockIdx.x, b = blockIdx.y;
  short* row = SA + ((size_t)b * Spad + t) * Spad;
  const int tid = threadIdx.x;

  float mx = -1e30f;
  for (int i = tid; i < S; i += 256) {
    float v = bf2f(row[i]) * scale;
    buf[i] = v;
    mx = fmaxf(mx, v);
  }
  for (int off = 32; off; off >>= 1) mx = fmaxf(mx, __shfl_down(mx, off, 64));
  if ((tid & 63) == 0) red[tid >> 6] = mx;
  __syncthreads();
  if (tid == 0) {
    float m = red[0];
    for (int w = 1; w < 4; w++) m = fmaxf(m, red[w]);
    red[0] = m;
  }
  __syncthreads();
  mx = red[0];

  float sum = 0.f;
  for (int i = tid; i < S; i += 256) {
    float e = __expf(buf[i] - mx);
    buf[i] = e;
    sum += e;
  }
  for (int off = 32; off; off >>= 1) sum += __shfl_down(sum, off, 64);
  if ((tid & 63) == 0) red[4 + (tid >> 6)] = sum;
  __syncthreads();
  if (tid == 0) red[4] = 1.0f / (red[4] + red[5] + red[6] + red[7]);
  __syncthreads();
  const float rinv = red[4];

  for (int i = tid; i < S; i += 256) row[i] = f2bf(buf[i] * rinv);
  for (int i = S + tid; i < Spad; i += 256) row[i] = 0;
}

// ---------------------------------------------------------------------------
__global__ __launch_bounds__(256)
void wtrans(const float* __restrict__ W, short* __restrict__ WT)
{
  __shared__ float tile[32][33];
  const int bn = blockIdx.x * 32, bk = blockIdx.y * 32;
  const int tx = threadIdx.x & 31, ty = threadIdx.x >> 5;  // 32 x 8
#pragma unroll
  for (int j = 0; j < 4; j++)
    tile[ty + j * 8][tx] = W[(size_t)(bk + ty + j * 8) * DIM + bn + tx];
  __syncthreads();
#pragma unroll
  for (int j = 0; j < 4; j++)
    WT[(size_t)(bn + ty + j * 8) * DIM + bk + tx] = f2bf(tile[tx][ty + j * 8]);
}

// ---------------------------------------------------------------------------
__global__ __launch_bounds__(256)
void assemble0(const float* __restrict__ seg0, short* __restrict__ X)
{
  const int Spad = 2176;
  const int b = blockIdx.y;
  const size_t lin = ((size_t)blockIdx.x * 256 + threadIdx.x) * 4;
  const int t = (int)(lin >> 10), d = (int)(lin & 1023);
  float4 v = make_float4(0.f, 0.f, 0.f, 0.f);
  if (t >= 1 && t <= SEQL)
    v = *(const float4*)(seg0 + ((size_t)b * SEQL + (t - 1)) * DIM + d);
  union { short s[4]; ull u; } o;
  o.s[0] = f2bf(v.x); o.s[1] = f2bf(v.y); o.s[2] = f2bf(v.z); o.s[3] = f2bf(v.w);
  *(ull*)(X + (size_t)b * Spad * DIM + lin) = o.u;
}

__global__ __launch_bounds__(256)
void assembleS(const float* __restrict__ seg1, const float* __restrict__ prompt,
               short* __restrict__ X)
{
  const int Spad = 640;
  const int b = blockIdx.y;
  const size_t lin = ((size_t)blockIdx.x * 256 + threadIdx.x) * 4;
  const int t = (int)(lin >> 10), d = (int)(lin & 1023);
  float4 v = make_float4(0.f, 0.f, 0.f, 0.f);
  if (t == 0 || t == JSUM + 1)
    v = *(const float4*)(prompt + d);
  else if (t >= 1 && t <= JSUM)
    v = *(const float4*)(seg1 + ((size_t)b * SEQL + (t - 1)) * DIM + d);
  union { short s[4]; ull u; } o;
  o.s[0] = f2bf(v.x); o.s[1] = f2bf(v.y); o.s[2] = f2bf(v.z); o.s[3] = f2bf(v.w);
  *(ull*)(X + (size_t)b * Spad * DIM + lin) = o.u;
}

__global__ __launch_bounds__(256)
void assemble1(const float* __restrict__ seg0, const float* __restrict__ seg1,
               const float* __restrict__ P1, short* __restrict__ X)
{
  const int Spad = 2176;
  const int b = blockIdx.y;
  const size_t lin = ((size_t)blockIdx.x * 256 + threadIdx.x) * 4;
  const int t = (int)(lin >> 10), d = (int)(lin & 1023);
  float4 v = make_float4(0.f, 0.f, 0.f, 0.f);
  if (t < 32)
    v = *(const float4*)(seg0 + ((size_t)b * SEQL + (SEQL - 32 + t)) * DIM + d);
  else if (t == 32 || t == 2081)
    v = *(const float4*)(P1 + (size_t)b * DIM + d);
  else if (t >= 33 && t <= 2080)
    v = *(const float4*)(seg1 + ((size_t)b * SEQL + (t - 33)) * DIM + d);
  union { short s[4]; ull u; } o;
  o.s[0] = f2bf(v.x); o.s[1] = f2bf(v.y); o.s[2] = f2bf(v.z); o.s[3] = f2bf(v.w);
  *(ull*)(X + (size_t)b * Spad * DIM + lin) = o.u;
}

// ---------------------------------------------------------------------------
__global__ __launch_bounds__(256)
void mem_proj(const float* __restrict__ Sb, const float* __restrict__ M1,
              const float* __restrict__ Wq_mem, const float* __restrict__ bq_mem,
              const float* __restrict__ Wk_mem, const float* __restrict__ bk_mem,
              float* __restrict__ Qn, float* __restrict__ Kp)
{
  const int n = blockIdx.x * 256 + threadIdx.x;
  const int b = blockIdx.y;
  const int w = blockIdx.z;
  const float* x    = w ? M1 : Sb;
  const float* W    = w ? Wk_mem : Wq_mem;
  const float* bias = w ? bk_mem : bq_mem;
  float* o          = w ? Kp : Qn;
  const float* xr = x + (size_t)b * DIM;
  float s = bias[n];
  for (int k = 0; k < DIM; k++) s += xr[k] * W[(size_t)k * DIM + n];
  o[(size_t)b * DIM + n] = s;
}

__global__ __launch_bounds__(256)
void mem_attn(const float* __restrict__ Qn, const float* __restrict__ Kp,
              const float* __restrict__ M1, float* __restrict__ P1, float scale)
{
  __shared__ float red[256];
  __shared__ float w8[8];
  const int b = blockIdx.x, tid = threadIdx.x;
  for (int bp = 0; bp < NBATCH; bp++) {
    float p = 0.f;
    for (int k = tid; k < DIM; k += 256)
      p += Qn[(size_t)b * DIM + k] * Kp[(size_t)bp * DIM + k];
    red[tid] = p; __syncthreads();
    for (int off = 128; off; off >>= 1) {
      if (tid < off) red[tid] += red[tid + off];
      __syncthreads();
    }
    if (tid == 0) w8[bp] = red[0] * scale;
    __syncthreads();
  }
  if (tid == 0) {
    float m = w8[0];
    for (int i = 1; i < NBATCH; i++) m = fmaxf(m, w8[i]);
    float s = 0.f;
    for (int i = 0; i < NBATCH; i++) { w8[i] = __expf(w8[i] - m); s += w8[i]; }
    for (int i = 0; i < NBATCH; i++) w8[i] /= s;
  }
  __syncthreads();
  for (int d = tid; d < DIM; d += 256) {
    float a = 0.f;
    for (int bp = 0; bp < NBATCH; bp++) a += w8[bp] * M1[(size_t)bp * DIM + d];
    P1[(size_t)b * DIM + d] = a;
  }
}

// ---------------------------------------------------------------------------
extern "C" void kernel_launch(void* const* d_in, const int* in_sizes, int n_in,
                              void* d_out, int out_size, void* d_ws, size_t ws_size,
                              hipStream_t stream)
{
  const float* seg0   = (const float*)d_in[0];
  const float* seg1   = (const float*)d_in[1];
  const float* prompt = (const float*)d_in[2];
  const float* Wq_mem = (const float*)d_in[3];
  const float* bq_mem = (const float*)d_in[4];
  const float* Wk_mem = (const float*)d_in[5];
  const float* bk_mem = (const float*)d_in[6];
  const float* Wq     = (const float*)d_in[7];
  const float* bq     = (const float*)d_in[8];
  const float* Wk     = (const float*)d_in[9];
  const float* bk     = (const float*)d_in[10];
  const float* Wv     = (const float*)d_in[11];
  const float* bv     = (const float*)d_in[12];
  const float* Wo     = (const float*)d_in[13];
  const float* bo     = (const float*)d_in[14];
  float* outp = (float*)d_out;

  const int   SPMAX = 2176;
  const size_t WSZ  = (size_t)DIM * DIM * 2;
  const size_t XSZ  = (size_t)NBATCH * SPMAX * DIM * 2;
  const size_t SASZ = (size_t)NBATCH * SPMAX * SPMAX * 2;
  const size_t VSZ  = (size_t)NBATCH * DIM * 4;

  char* p = (char*)d_ws;
  short* WqT = (short*)p; p += WSZ;
  short* WkT = (short*)p; p += WSZ;
  short* WvT = (short*)p; p += WSZ;
  short* WoT = (short*)p; p += WSZ;
  short* X   = (short*)p; p += XSZ;
  short* Qb  = (short*)p; p += XSZ;
  short* Kb  = (short*)p; p += XSZ;
  short* Vt  = (short*)p; p += XSZ;
  short* Ctx = (short*)p; p += XSZ;
  short* SA  = (short*)p; p += SASZ;
  float* M1b = (float*)p; p += VSZ;
  float* Sb  = (float*)p; p += VSZ;
  float* Qn  = (float*)p; p += VSZ;
  float* Kp  = (float*)p; p += VSZ;
  float* P1  = (float*)p; p += VSZ;

  const float scale = 0.03125f;   // 1/sqrt(1024)
  dim3 blk(256, 1, 1);

  auto run_backbone = [&](int Spad, int S,
                          float* o_dst, int t_lo, int t_hi, int outT,
                          float* o_sp, int t_sp) {
    const int MT = NBATCH * Spad / 128;
    // Q = X Wq^T + bq   (SWIZ=2: A-panel sharers on one XCD; MT % 8 == 0)
    gemm_nt<1, 2><<<dim3(MT, DIM / 128, 1), blk, 0, stream>>>(
        X, 0ULL, WqT, 0ULL, Qb, 0ULL, DIM, DIM, bq,
        nullptr, 0, 0, 0, nullptr, -1, Spad);
    // K = X Wk^T + bk
    gemm_nt<1, 2><<<dim3(MT, DIM / 128, 1), blk, 0, stream>>>(
        X, 0ULL, WkT, 0ULL, Kb, 0ULL, DIM, DIM, bk,
        nullptr, 0, 0, 0, nullptr, -1, Spad);
    // Vt[b] (D x Spad) = NT(WvT, X_b) + bv[m]   (batch->XCD swizzle)
    gemm_nt<2, 1><<<dim3(Spad / 128, DIM / 128, NBATCH), blk, 0, stream>>>(
        WvT, 0ULL, X, (ull)Spad * DIM,
        Vt, (ull)DIM * Spad, Spad, DIM, bv,
        nullptr, 0, 0, 0, nullptr, -1, Spad);
    // scores[b] = Q_b K_b^T   (batch->XCD swizzle)
    gemm_nt<0, 1><<<dim3(Spad / 128, Spad / 128, NBATCH), blk, 0, stream>>>(
        Qb, (ull)Spad * DIM, Kb, (ull)Spad * DIM,
        SA, (ull)Spad * Spad, Spad, DIM, nullptr,
        nullptr, 0, 0, 0, nullptr, -1, Spad);
    softmax_rows<<<dim3(Spad, NBATCH), blk, 0, stream>>>(SA, Spad, S, scale);
    // ctx[b] = attn_b Vt_b^T   (batch->XCD swizzle)
    gemm_nt<0, 1><<<dim3(DIM / 128, Spad / 128, NBATCH), blk, 0, stream>>>(
        SA, (ull)Spad * Spad, Vt, (ull)DIM * Spad,
        Ctx, (ull)Spad * DIM, DIM, Spad, nullptr,
        nullptr, 0, 0, 0, nullptr, -1, Spad);
    // H = ctx Wo^T + bo, scattered to outputs
    gemm_nt<3, 2><<<dim3(MT, DIM / 128, 1), blk, 0, stream>>>(
        Ctx, 0ULL, WoT, 0ULL, nullptr, 0ULL, DIM, DIM, bo,
        o_dst, t_lo, t_hi, outT, o_sp, t_sp, Spad);
  };

  wtrans<<<dim3(32, 32), blk, 0, stream>>>(Wq, WqT);
  wtrans<<<dim3(32, 32), blk, 0, stream>>>(Wk, WkT);
  wtrans<<<dim3(32, 32), blk, 0, stream>>>(Wv, WvT);
  wtrans<<<dim3(32, 32), blk, 0, stream>>>(Wo, WoT);

  // Phase 0: backbone([P0, seg0, P0])  S=2050, Spad=2176
  assemble0<<<dim3(2176, NBATCH), blk, 0, stream>>>(seg0, X);
  run_backbone(2176, 2050, outp, 33, 2049, 2016, M1b, 2049);

  // Phase S: summarize(seg1)  S=514, Spad=640
  assembleS<<<dim3(640, NBATCH), blk, 0, stream>>>(seg1, prompt, X);
  run_backbone(640, 514, nullptr, 0, 0, 0, Sb, JSUM);

  // Memory attention (exact f32)
  mem_proj<<<dim3(DIM / 256, NBATCH, 2), blk, 0, stream>>>(
      Sb, M1b, Wq_mem, bq_mem, Wk_mem, bk_mem, Qn, Kp);
  mem_attn<<<dim3(NBATCH), blk, 0, stream>>>(Qn, Kp, M1b, P1, scale);

  // Phase 1: backbone([seg0[-32:], P1, seg1, P1])  S=2082, Spad=2176
  assemble1<<<dim3(2176, NBATCH), blk, 0, stream>>>(seg0, seg1, P1, X);
  run_backbone(2176, 2082, outp + (size_t)NBATCH * 2016 * DIM,
               33, 2081, 2048, nullptr, -1);
}